// Round 15
// baseline (338.272 us; speedup 1.0000x reference)
//
#include <hip/hip_runtime.h>

// B=64, S1=1024, S2=1024, DV=256.
// softmax(sx[i]+sk[j]+b0) over j == softmax(sk)[j]  (shift invariance)
// => attn row identical for all i; out[b,i,:] = sum_j softmax(sk)[j]*value[b,j,:].
// x, W[0:3], b never affect the output.
//
// SINGLE fused kernel, 1024 blocks = 64 batches x 16 chunks:
//   phase 1: block (b,chunk) computes batch softmax stats (12 KB key read,
//     L2-shared among siblings) and its 64-row PV partial; publishes it with
//     a device-scope release flag (magic value; ws is poisoned 0xAA != magic
//     before every launch, so no init pass needed).
//   phase 2: block spins (agent-scope acquire) on its batch's 16 flags, sums
//     the 16 partials (L2-resident), and NT-broadcast-writes its 64 output
//     rows. Per-batch pipelining overlaps the write phase with other
//     batches' read phase; saves one kernel launch + inter-kernel barrier.

#define NB 64
#define S1V 1024
#define S2V 1024
#define DVV 256
#define NCHUNK 16
#define JPC (S2V / NCHUNK)   // 64 j per chunk
#define FLAG_MAGIC 0x13579BDFu

typedef float nf4 __attribute__((ext_vector_type(4)));

// ws layout: partial = NB*NCHUNK*DVV floats (1 MB) @ 0
//            flags   = NB*NCHUNK uint (4 KB)     @ 1048576

__global__ __launch_bounds__(256) void k_fused(const float* __restrict__ key,
                                               const float* __restrict__ value,
                                               const float* __restrict__ W,
                                               float* __restrict__ partial,
                                               unsigned int* __restrict__ flags,
                                               float* __restrict__ out) {
    const int b     = blockIdx.x >> 4;          // / NCHUNK
    const int chunk = blockIdx.x & (NCHUNK - 1);
    const int t     = threadIdx.x;
    const int wave  = t >> 6, lane = t & 63;

    const float wk0 = W[3], wk1 = W[4], wk2 = W[5];

    // ---- phase 1a: softmax stats over all 1024 j (thread t owns 4t..4t+3) ----
    const float4* k4 = (const float4*)(key + (size_t)b * S2V * 3);
    float4 a = k4[3 * t + 0];
    float4 c = k4[3 * t + 1];
    float4 d = k4[3 * t + 2];
    float sk0 = fmaf(a.x, wk0, fmaf(a.y, wk1, a.z * wk2));
    float sk1 = fmaf(a.w, wk0, fmaf(c.x, wk1, c.y * wk2));
    float sk2 = fmaf(c.z, wk0, fmaf(c.w, wk1, d.x * wk2));
    float sk3 = fmaf(d.y, wk0, fmaf(d.z, wk1, d.w * wk2));

    __shared__ float redm[4], reds[4];

    float m = fmaxf(fmaxf(sk0, sk1), fmaxf(sk2, sk3));
    #pragma unroll
    for (int off = 32; off; off >>= 1) m = fmaxf(m, __shfl_xor(m, off));
    if (lane == 0) redm[wave] = m;
    __syncthreads();
    m = fmaxf(fmaxf(redm[0], redm[1]), fmaxf(redm[2], redm[3]));

    float e0 = __expf(sk0 - m), e1 = __expf(sk1 - m);
    float e2 = __expf(sk2 - m), e3 = __expf(sk3 - m);
    float s = e0 + e1 + e2 + e3;
    #pragma unroll
    for (int off = 32; off; off >>= 1) s += __shfl_xor(s, off);
    if (lane == 0) reds[wave] = s;
    __syncthreads();
    s = reds[0] + reds[1] + reds[2] + reds[3];
    const float inv = 1.0f / s;

    // ---- phase 1b: stash this chunk's 64 p values ----
    __shared__ float p_lds[JPC];
    const int tlo = chunk * (JPC / 4);          // 16 threads own this chunk
    if (t >= tlo && t < tlo + JPC / 4) {
        const int q = (t - tlo) * 4;
        p_lds[q + 0] = e0 * inv;
        p_lds[q + 1] = e1 * inv;
        p_lds[q + 2] = e2 * inv;
        p_lds[q + 3] = e3 * inv;
    }
    __syncthreads();

    // ---- phase 1c: PV partial, wave w owns j = chunk*64 + w*16 + i ----
    const float4* v4 = (const float4*)(value + (size_t)b * S2V * DVV);
    const int jbase = chunk * JPC + wave * (JPC / 4);
    float4 acc = make_float4(0.f, 0.f, 0.f, 0.f);
    #pragma unroll
    for (int i = 0; i < JPC / 4; ++i) {
        const float pj = p_lds[wave * (JPC / 4) + i];
        float4 v = v4[(size_t)(jbase + i) * 64 + lane];
        acc.x = fmaf(pj, v.x, acc.x);
        acc.y = fmaf(pj, v.y, acc.y);
        acc.z = fmaf(pj, v.z, acc.z);
        acc.w = fmaf(pj, v.w, acc.w);
    }

    __shared__ float4 accl[256];
    accl[t] = acc;
    __syncthreads();
    if (wave == 0) {
        float4 r0 = accl[lane];
        float4 r1 = accl[64 + lane];
        float4 r2 = accl[128 + lane];
        float4 r3 = accl[192 + lane];
        r0.x += r1.x + r2.x + r3.x;
        r0.y += r1.y + r2.y + r3.y;
        r0.z += r1.z + r2.z + r3.z;
        r0.w += r1.w + r2.w + r3.w;
        ((float4*)(partial + ((size_t)b * NCHUNK + chunk) * DVV))[lane] = r0;
    }

    // ---- publish: device fence (stores visible agent-wide), then release flag ----
    __threadfence();
    __syncthreads();
    if (t == 0) {
        __hip_atomic_store(&flags[b * NCHUNK + chunk], FLAG_MAGIC,
                           __ATOMIC_RELEASE, __HIP_MEMORY_SCOPE_AGENT);
    }

    // ---- phase 2a: every thread acquire-spins on one of the 16 flags ----
    {
        const unsigned int* f = &flags[b * NCHUNK + (t & (NCHUNK - 1))];
        while (__hip_atomic_load(f, __ATOMIC_ACQUIRE,
                                 __HIP_MEMORY_SCOPE_AGENT) != FLAG_MAGIC) { }
    }
    __syncthreads();

    // ---- phase 2b: sum 16 partials (coalesced; L2-resident) ----
    float rsum = 0.f;
    const float* pb = partial + (size_t)b * NCHUNK * DVV;
    #pragma unroll
    for (int c2 = 0; c2 < NCHUNK; ++c2)
        rsum += pb[c2 * DVV + t];

    __shared__ float row_lds[DVV];
    row_lds[t] = rsum;
    __syncthreads();

    nf4 rv = ((const nf4*)row_lds)[lane];

    // ---- phase 2c: NT-broadcast 64 rows (rows chunk*64 .. chunk*64+63) ----
    nf4* ob = (nf4*)(out + ((size_t)b * S1V + (size_t)chunk * JPC) * DVV);
    #pragma unroll
    for (int k = 0; k < 16; ++k) {
        const int row = wave + k * 4;           // wave w covers rows w,w+4,...,w+60
        __builtin_nontemporal_store(rv, &ob[(size_t)row * 64 + lane]);
    }
}

extern "C" void kernel_launch(void* const* d_in, const int* in_sizes, int n_in,
                              void* d_out, int out_size, void* d_ws, size_t ws_size,
                              hipStream_t stream) {
    // inputs: 0=x (unused), 1=key, 2=value, 3=W, 4=b (unused)
    const float* key   = (const float*)d_in[1];
    const float* value = (const float*)d_in[2];
    const float* W     = (const float*)d_in[3];
    float* out = (float*)d_out;

    float*        partial = (float*)d_ws;                        // 1 MB
    unsigned int* flags   = (unsigned int*)((char*)d_ws + (1u << 20)); // 4 KB

    k_fused<<<NB * NCHUNK, 256, 0, stream>>>(key, value, W, partial, flags, out);
}

// Round 16
// 119.643 us; speedup vs baseline: 2.8273x; 2.8273x over previous
//
#include <hip/hip_runtime.h>

// B=64, S1=1024, S2=1024, DV=256.
// softmax(sx[i]+sk[j]+b0) over j == softmax(sk)[j]  (shift invariance)
// => attn row identical for all i; out[b,i,:] = sum_j softmax(sk)[j]*value[b,j,:].
// x, W[0:3], b never affect the output.
//
// Two kernels (measured 119.9 us total in round 14; fused flag-sync variant
// measured 338 us in round 15 — cross-XCD spin-wait cost >> launch overhead):
//  A (k_pv): 1024 blocks = 64 batches x 16 chunks. Each block recomputes the
//    batch softmax stats (12 KB key read, L2-cached across the 16 sibling
//    blocks), then reduces its 64-row value chunk. Writes 1 MB of partials.
//  B (k_out): 8192 blocks. Sums the 16 partials per (b,d) (L2-resident) and
//    broadcast-writes the 64 MB output with non-temporal float4 stores.

#define NB 64
#define S1V 1024
#define S2V 1024
#define DVV 256
#define NCHUNK 16
#define JPC (S2V / NCHUNK)   // 64 j per chunk

typedef float nf4 __attribute__((ext_vector_type(4)));  // nontemporal-capable float4

// ws layout: partial = NB*NCHUNK*DVV floats = 1 MB @ offset 0

__global__ __launch_bounds__(256) void k_pv(const float* __restrict__ key,
                                            const float* __restrict__ value,
                                            const float* __restrict__ W,
                                            float* __restrict__ partial) {
    const int b     = blockIdx.x >> 4;          // / NCHUNK
    const int chunk = blockIdx.x & (NCHUNK - 1);
    const int t     = threadIdx.x;
    const int wave  = t >> 6, lane = t & 63;

    const float wk0 = W[3], wk1 = W[4], wk2 = W[5];

    // ---- softmax stats over all 1024 j (thread t owns j = 4t..4t+3) ----
    const float4* k4 = (const float4*)(key + (size_t)b * S2V * 3);
    float4 a = k4[3 * t + 0];
    float4 c = k4[3 * t + 1];
    float4 d = k4[3 * t + 2];
    float sk0 = fmaf(a.x, wk0, fmaf(a.y, wk1, a.z * wk2));
    float sk1 = fmaf(a.w, wk0, fmaf(c.x, wk1, c.y * wk2));
    float sk2 = fmaf(c.z, wk0, fmaf(c.w, wk1, d.x * wk2));
    float sk3 = fmaf(d.y, wk0, fmaf(d.z, wk1, d.w * wk2));

    __shared__ float redm[4], reds[4];

    float m = fmaxf(fmaxf(sk0, sk1), fmaxf(sk2, sk3));
    #pragma unroll
    for (int off = 32; off; off >>= 1) m = fmaxf(m, __shfl_xor(m, off));
    if (lane == 0) redm[wave] = m;
    __syncthreads();
    m = fmaxf(fmaxf(redm[0], redm[1]), fmaxf(redm[2], redm[3]));

    float e0 = __expf(sk0 - m), e1 = __expf(sk1 - m);
    float e2 = __expf(sk2 - m), e3 = __expf(sk3 - m);
    float s = e0 + e1 + e2 + e3;
    #pragma unroll
    for (int off = 32; off; off >>= 1) s += __shfl_xor(s, off);
    if (lane == 0) reds[wave] = s;
    __syncthreads();
    s = reds[0] + reds[1] + reds[2] + reds[3];
    const float inv = 1.0f / s;

    // ---- stash this chunk's 64 p values ----
    __shared__ float p_lds[JPC];
    const int tlo = chunk * (JPC / 4);          // 16 threads own this chunk
    if (t >= tlo && t < tlo + JPC / 4) {
        const int q = (t - tlo) * 4;
        p_lds[q + 0] = e0 * inv;
        p_lds[q + 1] = e1 * inv;
        p_lds[q + 2] = e2 * inv;
        p_lds[q + 3] = e3 * inv;
    }
    __syncthreads();

    // ---- PV partial: wave w owns j = chunk*64 + w*16 + i ----
    const float4* v4 = (const float4*)(value + (size_t)b * S2V * DVV);
    const int jbase = chunk * JPC + wave * (JPC / 4);
    float4 acc = make_float4(0.f, 0.f, 0.f, 0.f);
    #pragma unroll
    for (int i = 0; i < JPC / 4; ++i) {
        const float pj = p_lds[wave * (JPC / 4) + i];
        float4 v = v4[(size_t)(jbase + i) * 64 + lane];
        acc.x = fmaf(pj, v.x, acc.x);
        acc.y = fmaf(pj, v.y, acc.y);
        acc.z = fmaf(pj, v.z, acc.z);
        acc.w = fmaf(pj, v.w, acc.w);
    }

    __shared__ float4 accl[256];
    accl[t] = acc;
    __syncthreads();
    if (wave == 0) {
        float4 r0 = accl[lane];
        float4 r1 = accl[64 + lane];
        float4 r2 = accl[128 + lane];
        float4 r3 = accl[192 + lane];
        r0.x += r1.x + r2.x + r3.x;
        r0.y += r1.y + r2.y + r3.y;
        r0.z += r1.z + r2.z + r3.z;
        r0.w += r1.w + r2.w + r3.w;
        ((float4*)(partial + ((size_t)b * NCHUNK + chunk) * DVV))[lane] = r0;
    }
}

__global__ __launch_bounds__(256) void k_out(const float* __restrict__ partial,
                                             float* __restrict__ out) {
    // 128 blocks per batch; each block writes 8 rows of 256 floats.
    const int b    = blockIdx.x >> 7;
    const int rt   = blockIdx.x & 127;
    const int t    = threadIdx.x;
    const int d4   = t & 63;
    const int rsub = t >> 6;                    // 0..3

    // wave `rsub` sums chunks [rsub*4, rsub*4+4) for its d4
    const float4* pp = (const float4*)(partial + (size_t)b * NCHUNK * DVV);
    float4 acc = make_float4(0.f, 0.f, 0.f, 0.f);
    #pragma unroll
    for (int c = rsub * 4; c < rsub * 4 + 4; ++c) {
        float4 v = pp[c * 64 + d4];
        acc.x += v.x; acc.y += v.y; acc.z += v.z; acc.w += v.w;
    }
    __shared__ float4 accl[256];
    accl[t] = acc;
    __syncthreads();
    float4 r = accl[d4];
    float4 r1 = accl[64 + d4];
    float4 r2 = accl[128 + d4];
    float4 r3 = accl[192 + d4];
    r.x += r1.x + r2.x + r3.x;
    r.y += r1.y + r2.y + r3.y;
    r.z += r1.z + r2.z + r3.z;
    r.w += r1.w + r2.w + r3.w;

    nf4 rv = { r.x, r.y, r.z, r.w };
    nf4* out4 = (nf4*)(out + ((size_t)b * S1V + (size_t)rt * 8) * DVV);
    __builtin_nontemporal_store(rv, &out4[(size_t)rsub * 64 + d4]);
    __builtin_nontemporal_store(rv, &out4[(size_t)(rsub + 4) * 64 + d4]);
}

extern "C" void kernel_launch(void* const* d_in, const int* in_sizes, int n_in,
                              void* d_out, int out_size, void* d_ws, size_t ws_size,
                              hipStream_t stream) {
    // inputs: 0=x (unused), 1=key, 2=value, 3=W, 4=b (unused)
    const float* key   = (const float*)d_in[1];
    const float* value = (const float*)d_in[2];
    const float* W     = (const float*)d_in[3];
    float* out = (float*)d_out;

    float* partial = (float*)d_ws;   // 1 MB

    k_pv<<<NB * NCHUNK, 256, 0, stream>>>(key, value, W, partial);
    k_out<<<NB * 128, 256, 0, stream>>>(partial, out);
}